// Round 4
// baseline (1771.740 us; speedup 1.0000x reference)
//
#include <hip/hip_runtime.h>
#include <hip/hip_bf16.h>

#define NB 32
#define L 1024
#define H 1024

typedef __attribute__((ext_vector_type(4))) float floatx4;
typedef __attribute__((ext_vector_type(8))) short shortx8;
typedef __attribute__((ext_vector_type(8))) unsigned short ushortx8;

__device__ __forceinline__ unsigned short f2bf(float f) {
    union { float f; unsigned int u; } v; v.f = f;
    unsigned int u = v.u;
    u += 0x7fffu + ((u >> 16) & 1u);   // round-to-nearest-even
    return (unsigned short)(u >> 16);
}
__device__ __forceinline__ float bf2f(unsigned short h) {
    union { unsigned int u; float f; } v; v.u = ((unsigned int)h) << 16;
    return v.f;
}

// ---- dtype detection: bf16 vs fp32 materialization of the float tensors ----
__global__ void detect_kernel(const unsigned short* a, int* flag) {
    int tid = threadIdx.x;
    unsigned short u = a[tid];
    int e = (u >> 7) & 0xff;
    int ok = (u == 0) || (e >= 116 && e <= 136);
    unsigned long long ball = __ballot(ok != 0);
    if (tid == 0) flag[0] = (__popcll(ball) >= 56) ? 1 : 0;
}

__device__ __forceinline__ void store_out(void* out, size_t eidx, float v, int isbf) {
    if (isbf) ((unsigned short*)out)[eidx] = f2bf(v);
    else      ((float*)out)[eidx] = v;
}

// mean over the sequence axis: mean_x[b,h] = (1/L) sum_s x[b,s,h]
__global__ void mean_kernel(const void* a, const void* b, const int* flag,
                            float* mean_a, float* mean_b) {
    int idx = blockIdx.x * blockDim.x + threadIdx.x;  // (b,h) flat
    int bi = idx >> 10;
    int h = idx & (H - 1);
    const void* src = blockIdx.y ? b : a;
    float* dst = blockIdx.y ? mean_b : mean_a;
    int isbf = flag[0];
    size_t base = (size_t)bi * L * H + h;
    float s = 0.f;
    if (isbf) {
        const unsigned short* p = (const unsigned short*)src;
        for (int t = 0; t < L; ++t) s += bf2f(p[base + (size_t)t * H]);
    } else {
        const float* p = (const float*)src;
        for (int t = 0; t < L; ++t) s += p[base + (size_t)t * H];
    }
    dst[idx] = s * (1.f / (float)L);
}

// S = A.B^T * tau ; w = mask ? exp(S) : 0   (bf16, to ws; batch-chunked)
__global__ __launch_bounds__(256) void score_kernel(
    const void* A, const void* Bm, const int* mask_a, const int* mask_b,
    const void* temp, const int* flag, unsigned short* w, int b0) {
    __shared__ __align__(16) unsigned short As[128][40];
    __shared__ __align__(16) unsigned short Bs[128][40];
    int bi_l = blockIdx.z;
    int bi = b0 + bi_l;
    int s0 = blockIdx.y * 128, t0 = blockIdx.x * 128;
    int isbf = flag[0];
    float tv = isbf ? bf2f(((const unsigned short*)temp)[0]) : ((const float*)temp)[0];
    int tid = threadIdx.x;
    int wid = tid >> 6, lane = tid & 63;
    int wm = wid >> 1, wn = wid & 1;
    int lane15 = lane & 15, quad = lane >> 4;

    floatx4 acc[4][4];
#pragma unroll
    for (int i = 0; i < 4; ++i)
#pragma unroll
        for (int j = 0; j < 4; ++j)
#pragma unroll
            for (int r = 0; r < 4; ++r) acc[i][j][r] = 0.f;

    size_t baseA = (size_t)bi * L * H + (size_t)s0 * H;
    size_t baseB = (size_t)bi * L * H + (size_t)t0 * H;

    for (int k0 = 0; k0 < H; k0 += 32) {
        // 16B staging: its 0-1 load A-tile, its 2-3 load B-tile (wave-uniform)
#pragma unroll
        for (int it = 0; it < 4; ++it) {
            int idx = it * 256 + tid;
            int opA = (it < 2);
            int j = idx & 511;
            int r = j >> 2, c = (j & 3) * 8;
            size_t g = (opA ? baseA : baseB) + (size_t)r * H + k0 + c;
            unsigned short* dst = opA ? &As[r][c] : &Bs[r][c];
            const void* src = opA ? A : Bm;
            if (isbf) {
                *(ushortx8*)dst = *(const ushortx8*)((const unsigned short*)src + g);
            } else {
                const float* p = (const float*)src + g;
                float4 v0 = *(const float4*)p;
                float4 v1 = *(const float4*)(p + 4);
                ushortx8 o;
                o[0] = f2bf(v0.x); o[1] = f2bf(v0.y); o[2] = f2bf(v0.z); o[3] = f2bf(v0.w);
                o[4] = f2bf(v1.x); o[5] = f2bf(v1.y); o[6] = f2bf(v1.z); o[7] = f2bf(v1.w);
                *(ushortx8*)dst = o;
            }
        }
        __syncthreads();
        shortx8 af[4], bfr[4];
#pragma unroll
        for (int i = 0; i < 4; ++i)
            af[i] = *(const shortx8*)&As[wm * 64 + i * 16 + lane15][quad * 8];
#pragma unroll
        for (int j = 0; j < 4; ++j)
            bfr[j] = *(const shortx8*)&Bs[wn * 64 + j * 16 + lane15][quad * 8];
#pragma unroll
        for (int i = 0; i < 4; ++i)
#pragma unroll
            for (int j = 0; j < 4; ++j)
                acc[i][j] = __builtin_amdgcn_mfma_f32_16x16x32_bf16(af[i], bfr[j], acc[i][j], 0, 0, 0);
        __syncthreads();
    }

    int mb[4];
#pragma unroll
    for (int j = 0; j < 4; ++j)
        mb[j] = mask_b[bi * L + t0 + wn * 64 + j * 16 + lane15];
    size_t wbase = (size_t)bi_l * L * L;
#pragma unroll
    for (int i = 0; i < 4; ++i) {
#pragma unroll
        for (int r = 0; r < 4; ++r) {
            int s = s0 + wm * 64 + i * 16 + quad * 4 + r;
            int ma = mask_a[bi * L + s];
#pragma unroll
            for (int j = 0; j < 4; ++j) {
                int t = t0 + wn * 64 + j * 16 + lane15;
                float sc = acc[i][j][r] * tv;
                float wv = (ma && mb[j]) ? __expf(sc) : 0.f;
                w[wbase + (size_t)s * L + t] = f2bf(wv);
            }
        }
    }
}

__global__ void row_sum_kernel(const unsigned short* w, float* row_l, int b0) {
    int row = blockIdx.x;           // local (chunk) row
    int tid = threadIdx.x;
    ushort4 v = ((const ushort4*)(w + (size_t)row * L))[tid];
    float s = bf2f(v.x) + bf2f(v.y) + bf2f(v.z) + bf2f(v.w);
#pragma unroll
    for (int off = 32; off > 0; off >>= 1) s += __shfl_down(s, off);
    __shared__ float red[4];
    if ((tid & 63) == 0) red[tid >> 6] = s;
    __syncthreads();
    if (tid == 0) row_l[b0 * L + row] = red[0] + red[1] + red[2] + red[3];
}

__global__ void col_sum_kernel(const unsigned short* w, float* col_l, int b0) {
    int bi_l = blockIdx.x >> 2;
    int t = ((blockIdx.x & 3) * 256) + threadIdx.x;
    const unsigned short* p = w + (size_t)bi_l * L * L + t;
    float s = 0.f;
    for (int ss = 0; ss < L; ss += 8) {
#pragma unroll
        for (int u = 0; u < 8; ++u) s += bf2f(p[(size_t)(ss + u) * L]);
    }
    col_l[(b0 + bi_l) * L + t] = s;
}

// feature_a[s,h] = mask_a[s] ? (sum_t w[s,t] b[t,h]) / row_l[s] : mean_b[h]
__global__ __launch_bounds__(256) void feat_a_kernel(
    const unsigned short* w, const void* Bm, const int* mask_a, const int* flag,
    const float* row_l, const float* mean_b, void* out, int b0) {
    __shared__ __align__(16) unsigned short Ws[128][40];  // [s][k=t]
    __shared__ __align__(16) unsigned short Bs[128][40];  // [h][k=t]
    int bi_l = blockIdx.z;
    int bi = b0 + bi_l;
    int s0 = blockIdx.y * 128, h0 = blockIdx.x * 128;
    int isbf = flag[0];
    int tid = threadIdx.x;
    int wid = tid >> 6, lane = tid & 63;
    int wm = wid >> 1, wn = wid & 1;
    int lane15 = lane & 15, quad = lane >> 4;

    floatx4 acc[4][4];
#pragma unroll
    for (int i = 0; i < 4; ++i)
#pragma unroll
        for (int j = 0; j < 4; ++j)
#pragma unroll
            for (int r = 0; r < 4; ++r) acc[i][j][r] = 0.f;

    size_t wbase = (size_t)bi_l * L * L + (size_t)s0 * L;
    size_t bbase = (size_t)bi * L * H;

    for (int k0 = 0; k0 < L; k0 += 32) {
        // A-operand (w rows): k-contiguous, 16B loads
#pragma unroll
        for (int it = 0; it < 2; ++it) {
            int idx = it * 256 + tid;
            int r = idx >> 2, c = (idx & 3) * 8;
            *(ushortx8*)&Ws[r][c] =
                *(const ushortx8*)&w[wbase + (size_t)r * L + k0 + c];
        }
        // B-operand (b): n-contiguous in global -> transpose into [n][k]
#pragma unroll
        for (int it = 0; it < 4; ++it) {
            int idx = it * 256 + tid;
            int n = idx & 127, kq = idx >> 7;
            unsigned short v4[4];
            if (isbf) {
                const unsigned short* p = (const unsigned short*)Bm;
#pragma unroll
                for (int u = 0; u < 4; ++u)
                    v4[u] = p[bbase + (size_t)(k0 + kq * 4 + u) * H + h0 + n];
            } else {
                const float* p = (const float*)Bm;
#pragma unroll
                for (int u = 0; u < 4; ++u)
                    v4[u] = f2bf(p[bbase + (size_t)(k0 + kq * 4 + u) * H + h0 + n]);
            }
            *(ushort4*)&Bs[n][kq * 4] = make_ushort4(v4[0], v4[1], v4[2], v4[3]);
        }
        __syncthreads();
        shortx8 af[4], bfr[4];
#pragma unroll
        for (int i = 0; i < 4; ++i)
            af[i] = *(const shortx8*)&Ws[wm * 64 + i * 16 + lane15][quad * 8];
#pragma unroll
        for (int j = 0; j < 4; ++j)
            bfr[j] = *(const shortx8*)&Bs[wn * 64 + j * 16 + lane15][quad * 8];
#pragma unroll
        for (int i = 0; i < 4; ++i)
#pragma unroll
            for (int j = 0; j < 4; ++j)
                acc[i][j] = __builtin_amdgcn_mfma_f32_16x16x32_bf16(af[i], bfr[j], acc[i][j], 0, 0, 0);
        __syncthreads();
    }

#pragma unroll
    for (int i = 0; i < 4; ++i) {
#pragma unroll
        for (int r = 0; r < 4; ++r) {
            int s = s0 + wm * 64 + i * 16 + quad * 4 + r;
            int ma = mask_a[bi * L + s];
            float scale = ma ? (1.f / row_l[bi * L + s]) : 0.f;
#pragma unroll
            for (int j = 0; j < 4; ++j) {
                int h = h0 + wn * 64 + j * 16 + lane15;
                float v = ma ? acc[i][j][r] * scale : mean_b[bi * H + h];
                store_out(out, (size_t)bi * L * H + (size_t)s * H + h, v, isbf);
            }
        }
    }
}

// feature_b[t,h] = mask_b[t] ? (sum_s w[s,t] a[s,h]) / col_l[t] : mean_a[h]
__global__ __launch_bounds__(256) void feat_b_kernel(
    const unsigned short* w, const void* Am, const int* mask_b, const int* flag,
    const float* col_l, const float* mean_a, void* out, int b0) {
    __shared__ __align__(16) unsigned short Ws[128][40];   // [t][k=s]
    __shared__ __align__(16) unsigned short As2[128][40];  // [h][k=s]
    int bi_l = blockIdx.z;
    int bi = b0 + bi_l;
    int t0 = blockIdx.y * 128, h0 = blockIdx.x * 128;
    int isbf = flag[0];
    int tid = threadIdx.x;
    int wid = tid >> 6, lane = tid & 63;
    int wm = wid >> 1, wn = wid & 1;
    int lane15 = lane & 15, quad = lane >> 4;

    floatx4 acc[4][4];
#pragma unroll
    for (int i = 0; i < 4; ++i)
#pragma unroll
        for (int j = 0; j < 4; ++j)
#pragma unroll
            for (int r = 0; r < 4; ++r) acc[i][j][r] = 0.f;

    size_t wbb = (size_t)bi_l * L * L;
    size_t abase = (size_t)bi * L * H;

    for (int k0 = 0; k0 < L; k0 += 32) {
        // A-operand: W^T[t][s] — transpose from w (always bf16)
#pragma unroll
        for (int it = 0; it < 4; ++it) {
            int idx = it * 256 + tid;
            int n = idx & 127, kq = idx >> 7;
            unsigned short v4[4];
#pragma unroll
            for (int u = 0; u < 4; ++u)
                v4[u] = w[wbb + (size_t)(k0 + kq * 4 + u) * L + t0 + n];
            *(ushort4*)&Ws[n][kq * 4] = make_ushort4(v4[0], v4[1], v4[2], v4[3]);
        }
        // B-operand: a[s,h] — transpose into [h][s]
#pragma unroll
        for (int it = 0; it < 4; ++it) {
            int idx = it * 256 + tid;
            int n = idx & 127, kq = idx >> 7;
            unsigned short v4[4];
            if (isbf) {
                const unsigned short* p = (const unsigned short*)Am;
#pragma unroll
                for (int u = 0; u < 4; ++u)
                    v4[u] = p[abase + (size_t)(k0 + kq * 4 + u) * H + h0 + n];
            } else {
                const float* p = (const float*)Am;
#pragma unroll
                for (int u = 0; u < 4; ++u)
                    v4[u] = f2bf(p[abase + (size_t)(k0 + kq * 4 + u) * H + h0 + n]);
            }
            *(ushort4*)&As2[n][kq * 4] = make_ushort4(v4[0], v4[1], v4[2], v4[3]);
        }
        __syncthreads();
        shortx8 af[4], bfr[4];
#pragma unroll
        for (int i = 0; i < 4; ++i)
            af[i] = *(const shortx8*)&Ws[wm * 64 + i * 16 + lane15][quad * 8];
#pragma unroll
        for (int j = 0; j < 4; ++j)
            bfr[j] = *(const shortx8*)&As2[wn * 64 + j * 16 + lane15][quad * 8];
#pragma unroll
        for (int i = 0; i < 4; ++i)
#pragma unroll
            for (int j = 0; j < 4; ++j)
                acc[i][j] = __builtin_amdgcn_mfma_f32_16x16x32_bf16(af[i], bfr[j], acc[i][j], 0, 0, 0);
        __syncthreads();
    }

    const size_t FEAT_B_OFF = (size_t)NB * L * H;
#pragma unroll
    for (int i = 0; i < 4; ++i) {
#pragma unroll
        for (int r = 0; r < 4; ++r) {
            int t = t0 + wm * 64 + i * 16 + quad * 4 + r;
            int mbv = mask_b[bi * L + t];
            float scale = mbv ? (1.f / col_l[bi * L + t]) : 0.f;
#pragma unroll
            for (int j = 0; j < 4; ++j) {
                int h = h0 + wn * 64 + j * 16 + lane15;
                float v = mbv ? acc[i][j][r] * scale : mean_a[bi * H + h];
                store_out(out, FEAT_B_OFF + (size_t)bi * L * H + (size_t)t * H + h, v, isbf);
            }
        }
    }
}

extern "C" void kernel_launch(void* const* d_in, const int* in_sizes, int n_in,
                              void* d_out, int out_size, void* d_ws, size_t ws_size,
                              hipStream_t stream) {
    const void* a = d_in[0];
    const void* b = d_in[1];
    const int* mask_a = (const int*)d_in[2];
    const int* mask_b = (const int*)d_in[3];
    const void* temp = d_in[4];

    // Workspace layout: small stats FIRST, then the (chunk-sized) score buffer.
    // Never assume ws_size: chunk the batch dim so w fits in what we're given.
    char* wsp = (char*)d_ws;
    float* row_l  = (float*)wsp;                       // NB*L
    float* col_l  = row_l + (size_t)NB * L;            // NB*L
    float* mean_a = col_l + (size_t)NB * L;            // NB*H
    float* mean_b = mean_a + (size_t)NB * H;           // NB*H
    int*   flag   = (int*)(mean_b + (size_t)NB * H);
    const size_t stats_bytes = ((size_t)NB * L * 2 + (size_t)NB * H * 2) * 4 + 256;
    unsigned short* w = (unsigned short*)(wsp + stats_bytes);

    const size_t w_batch_bytes = (size_t)L * L * 2;    // 2 MiB per batch (bf16)
    size_t wavail = (ws_size > stats_bytes) ? (ws_size - stats_bytes) : 0;
    int chunk = (int)(wavail / w_batch_bytes);
    if (chunk < 1) chunk = 1;
    if (chunk > NB) chunk = NB;

    detect_kernel<<<1, 64, 0, stream>>>((const unsigned short*)a, flag);
    mean_kernel<<<dim3(NB * H / 256, 2), 256, 0, stream>>>(a, b, flag, mean_a, mean_b);

    for (int b0 = 0; b0 < NB; b0 += chunk) {
        int nb = (NB - b0 < chunk) ? (NB - b0) : chunk;
        score_kernel<<<dim3(8, 8, nb), 256, 0, stream>>>(a, b, mask_a, mask_b, temp, flag, w, b0);
        row_sum_kernel<<<nb * L, 256, 0, stream>>>(w, row_l, b0);
        col_sum_kernel<<<nb * 4, 256, 0, stream>>>(w, col_l, b0);
        feat_a_kernel<<<dim3(8, 8, nb), 256, 0, stream>>>(w, b, mask_a, flag, row_l, mean_b, d_out, b0);
        feat_b_kernel<<<dim3(8, 8, nb), 256, 0, stream>>>(w, a, mask_b, flag, col_l, mean_a, d_out, b0);
    }
}